// Round 1
// 93.897 us; speedup vs baseline: 1.0367x; 1.0367x over previous
//
#include <hip/hip_runtime.h>
#include <hip/hip_bf16.h>

#define BH 16
#define L 2048
#define S 2048
#define DD 64
#define BM 64
#define BK 64
#define LDSPAD 8
#define LDW (BK + LDSPAD)   // 72 elements -> 144B row stride, 16B aligned

typedef __attribute__((ext_vector_type(4))) float f32x4;
typedef __bf16 bf16x8 __attribute__((ext_vector_type(8)));

union FragU {
  bf16x8 f;
  __hip_bfloat162 h2[4];
};

#define MFMA16(a, b, c) __builtin_amdgcn_mfma_f32_16x16x32_bf16((a), (b), (c), 0, 0, 0)

__device__ inline __hip_bfloat162 exp2pk(float al2, float nsl2, float k0,
                                         float k1) {
  float e0 = __builtin_amdgcn_exp2f(fmaf(al2, k0, nsl2));
  float e1 = __builtin_amdgcn_exp2f(fmaf(al2, k1, nsl2));
  return __float22bfloat162_rn(make_float2(e0, e1));
}

// ---------------------------------------------------------------------------
// prep: blocks [0,2048): K row sums (16 lanes per row).
//       blocks [2048,2560): V [bh][s][d] fp32 -> VT [bh][d][s] bf16 transpose.
// (unchanged from previous round; modeled ~5us, fully coalesced)
// ---------------------------------------------------------------------------
__global__ __launch_bounds__(256) void prep_kernel(
    const float* __restrict__ k, const float* __restrict__ v,
    float* __restrict__ ks, __hip_bfloat16* __restrict__ vt) {
  __shared__ __hip_bfloat16 tile[DD][LDW];
  int t = threadIdx.x;
  if (blockIdx.x < 2048) {
    int g = blockIdx.x * 256 + t;
    int row = g >> 4;
    int l16 = g & 15;
    float4 x = reinterpret_cast<const float4*>(k + (size_t)row * DD)[l16];
    float s = x.x + x.y + x.z + x.w;
    s += __shfl_xor(s, 1);
    s += __shfl_xor(s, 2);
    s += __shfl_xor(s, 4);
    s += __shfl_xor(s, 8);
    if (l16 == 0) ks[row] = s;
  } else {
    int bid = blockIdx.x - 2048;
    int s0 = (bid & 31) * 64;
    int bh = bid >> 5;
    int srow = t >> 4;
    int d4 = (t & 15) * 4;
#pragma unroll
    for (int kk = 0; kk < 4; ++kk) {
      int s = srow + kk * 16;
      float4 val = *reinterpret_cast<const float4*>(
          v + ((size_t)(bh * S + s0 + s)) * DD + d4);
      tile[d4 + 0][s] = __float2bfloat16(val.x);
      tile[d4 + 1][s] = __float2bfloat16(val.y);
      tile[d4 + 2][s] = __float2bfloat16(val.z);
      tile[d4 + 3][s] = __float2bfloat16(val.w);
    }
    __syncthreads();
    int dd = t >> 3;
    int j = t & 7;
#pragma unroll
    for (int kk = 0; kk < 2; ++kk) {
      int d = dd + kk * 32;
      uint4 val = *reinterpret_cast<const uint4*>(&tile[d][j * 8]);
      *reinterpret_cast<uint4*>(vt + ((size_t)(bh * DD + d)) * S + s0 + j * 8) =
          val;
    }
  }
}

// ---------------------------------------------------------------------------
// attn v2: 512 threads = 8 waves = 2 row-groups (32 rows) x 4 S-groups.
// Staging in groups of 4 tiles (32KB), double-buffered, ONE barrier per step
// (8 steps). Each tile read by only 2 waves (row amortization). Softmax
// denominator computed by MFMA against an all-ones B fragment (no VALU adds,
// no serial dsum chain). Partial acc/denoms combined via LDS tree at end.
// ---------------------------------------------------------------------------
__global__ __launch_bounds__(512, 4) void attn_kernel(
    const float* __restrict__ q, const __hip_bfloat16* __restrict__ vt,
    const float* __restrict__ ks, float* __restrict__ out) {
  int l0 = blockIdx.x * BM;
  int bh = blockIdx.y;

  // 2 bufs x 4 tiles x 64 x 72 bf16 = 73728 B; overlaid by combine buffer
  // (4 zones x 32 x 65 f32 = 33280 B, fits in buf0's footprint; buf1 region
  // [36864,73728) stays untouched by cmb so no barrier needed vs step-7 reads)
  __shared__ char smem[2 * 4 * DD * LDW * 2] __attribute__((aligned(16)));
  __shared__ float a_row[BM];
  __shared__ float red[16];
  __shared__ float drow[4][2][2][16];  // [sg][rg][rt][row]

  auto ldsVT = reinterpret_cast<__hip_bfloat16(*)[4][DD][LDW]>(smem);
  auto cmb = reinterpret_cast<float(*)[32][65]>(smem);

  int t = threadIdx.x;
  int lane = t & 63;
  int w = t >> 6;   // 0..7
  int rg = w >> 2;  // row-group 0/1 (rows rg*32..rg*32+31)
  int sg = w & 3;   // S-group: tiles  step*4 + sg
  int m = lane & 15;
  int qd = lane >> 4;

  const __hip_bfloat16* vtb = vt + (size_t)bh * DD * S;
  const float* ksb = ks + (size_t)bh * S;

  // staging map: 128 threads per tile-slot tg; thread covers row vd, 64B half
  int tg = t >> 7;
  int u = t & 127;
  int vd = u >> 1;
  int vh = u & 1;

  // --- prologue global prefetch: VT group 0 + first ks chunk
  const __hip_bfloat16* vs0 =
      vtb + (size_t)vd * S + tg * 64 + vh * 32;
  uint4 p0 = reinterpret_cast<const uint4*>(vs0)[0];
  uint4 p1 = reinterpret_cast<const uint4*>(vs0)[1];
  uint4 p2 = reinterpret_cast<const uint4*>(vs0)[2];
  uint4 p3 = reinterpret_cast<const uint4*>(vs0)[3];
  int kb0 = sg * 64;
  float4 kA0 = *reinterpret_cast<const float4*>(ksb + kb0 + qd * 8);
  float4 kA1 = *reinterpret_cast<const float4*>(ksb + kb0 + qd * 8 + 4);
  float4 kB0 = *reinterpret_cast<const float4*>(ksb + kb0 + 32 + qd * 8);
  float4 kB1 = *reinterpret_cast<const float4*>(ksb + kb0 + 32 + qd * 8 + 4);

  // --- qsum for this block's 64 rows: 8 lanes per row
  {
    int r = t >> 3;
    int p = t & 7;
    const float* qp = q + ((size_t)(bh * L + l0 + r)) * DD + p * 8;
    float4 x0 = reinterpret_cast<const float4*>(qp)[0];
    float4 x1 = reinterpret_cast<const float4*>(qp)[1];
    float s = (x0.x + x0.y + x0.z + x0.w) + (x1.x + x1.y + x1.z + x1.w);
    s += __shfl_xor(s, 1);
    s += __shfl_xor(s, 2);
    s += __shfl_xor(s, 4);
    if (p == 0) a_row[r] = s;
  }

  // --- per-head kmax/kmin (per-block; sel cancels in softmax ratio)
  {
    float4 y = *reinterpret_cast<const float4*>(ksb + t * 4);
    float mx = fmaxf(fmaxf(y.x, y.y), fmaxf(y.z, y.w));
    float mn = fminf(fminf(y.x, y.y), fminf(y.z, y.w));
#pragma unroll
    for (int off = 1; off < 64; off <<= 1) {
      mx = fmaxf(mx, __shfl_xor(mx, off));
      mn = fminf(mn, __shfl_xor(mn, off));
    }
    if (lane == 0) {
      red[w] = mx;
      red[8 + w] = mn;
    }
  }

  // --- store VT group 0 (compiler waits on the global loads)
  {
    uint4* dst = reinterpret_cast<uint4*>(&ldsVT[0][tg][vd][vh * 32]);
    dst[0] = p0;
    dst[1] = p1;
    dst[2] = p2;
    dst[3] = p3;
  }
  __syncthreads();

  float kmax = red[0], kmin = red[8];
#pragma unroll
  for (int i = 1; i < 8; ++i) {
    kmax = fmaxf(kmax, red[i]);
    kmin = fminf(kmin, red[8 + i]);
  }
  const float LOG2E = 1.44269504088896f;
  float ar0 = a_row[rg * 32 + m];
  float ar1 = a_row[rg * 32 + 16 + m];
  float al2_0 = ar0 * LOG2E, al2_1 = ar1 * LOG2E;
  float nsl2_0 = -al2_0 * ((ar0 > 0.f) ? kmax : kmin);
  float nsl2_1 = -al2_1 * ((ar1 > 0.f) ? kmax : kmin);

  FragU of;  // all-ones B fragment for denominator row-sum MFMAs
  {
    __hip_bfloat162 one2 = __float22bfloat162_rn(make_float2(1.f, 1.f));
    of.h2[0] = of.h2[1] = of.h2[2] = of.h2[3] = one2;
  }

  f32x4 acc0[4], acc1[4];
  f32x4 ad0 = (f32x4){0.f, 0.f, 0.f, 0.f};
  f32x4 ad1 = (f32x4){0.f, 0.f, 0.f, 0.f};
#pragma unroll
  for (int c = 0; c < 4; ++c) {
    acc0[c] = (f32x4){0.f, 0.f, 0.f, 0.f};
    acc1[c] = (f32x4){0.f, 0.f, 0.f, 0.f};
  }

  for (int step = 0; step < 8; ++step) {
    int buf = step & 1;

    // global prefetch of next 4-tile group (clamped at the tail)
    int sn = (step < 7) ? step + 1 : 7;
    const __hip_bfloat16* vs =
        vtb + (size_t)vd * S + (sn * 4 + tg) * 64 + vh * 32;
    uint4 n0 = reinterpret_cast<const uint4*>(vs)[0];
    uint4 n1 = reinterpret_cast<const uint4*>(vs)[1];
    uint4 n2 = reinterpret_cast<const uint4*>(vs)[2];
    uint4 n3 = reinterpret_cast<const uint4*>(vs)[3];

    // E fragments for this wave's tile (rows rg*32 + rt*16 + m)
    FragU fA0, fA1, fB0, fB1;  // [rt0 kslice0/1, rt1 kslice0/1]
    fA0.h2[0] = exp2pk(al2_0, nsl2_0, kA0.x, kA0.y);
    fA0.h2[1] = exp2pk(al2_0, nsl2_0, kA0.z, kA0.w);
    fA0.h2[2] = exp2pk(al2_0, nsl2_0, kA1.x, kA1.y);
    fA0.h2[3] = exp2pk(al2_0, nsl2_0, kA1.z, kA1.w);
    fA1.h2[0] = exp2pk(al2_0, nsl2_0, kB0.x, kB0.y);
    fA1.h2[1] = exp2pk(al2_0, nsl2_0, kB0.z, kB0.w);
    fA1.h2[2] = exp2pk(al2_0, nsl2_0, kB1.x, kB1.y);
    fA1.h2[3] = exp2pk(al2_0, nsl2_0, kB1.z, kB1.w);
    fB0.h2[0] = exp2pk(al2_1, nsl2_1, kA0.x, kA0.y);
    fB0.h2[1] = exp2pk(al2_1, nsl2_1, kA0.z, kA0.w);
    fB0.h2[2] = exp2pk(al2_1, nsl2_1, kA1.x, kA1.y);
    fB0.h2[3] = exp2pk(al2_1, nsl2_1, kA1.z, kA1.w);
    fB1.h2[0] = exp2pk(al2_1, nsl2_1, kB0.x, kB0.y);
    fB1.h2[1] = exp2pk(al2_1, nsl2_1, kB0.z, kB0.w);
    fB1.h2[2] = exp2pk(al2_1, nsl2_1, kB1.x, kB1.y);
    fB1.h2[3] = exp2pk(al2_1, nsl2_1, kB1.z, kB1.w);

    // prefetch next ks chunk (old values already consumed into fragments)
    int kbn = ((step < 7) ? (step + 1) * 4 + sg : 28 + sg) * 64;
    kA0 = *reinterpret_cast<const float4*>(ksb + kbn + qd * 8);
    kA1 = *reinterpret_cast<const float4*>(ksb + kbn + qd * 8 + 4);
    kB0 = *reinterpret_cast<const float4*>(ksb + kbn + 32 + qd * 8);
    kB1 = *reinterpret_cast<const float4*>(ksb + kbn + 32 + qd * 8 + 4);

    // denominator row-sums on the MFMA pipe (register-only)
    ad0 = MFMA16(fA0.f, of.f, ad0);
    ad0 = MFMA16(fA1.f, of.f, ad0);
    ad1 = MFMA16(fB0.f, of.f, ad1);
    ad1 = MFMA16(fB1.f, of.f, ad1);

    // PV: both row-tiles share each ds_read_b128 of the B tile
#pragma unroll
    for (int c = 0; c < 4; ++c) {
      uint4 b0 =
          *reinterpret_cast<const uint4*>(&ldsVT[buf][sg][c * 16 + m][qd * 8]);
      bf16x8 bb0 = __builtin_bit_cast(bf16x8, b0);
      acc0[c] = MFMA16(fA0.f, bb0, acc0[c]);
      acc1[c] = MFMA16(fB0.f, bb0, acc1[c]);
      uint4 b1 = *reinterpret_cast<const uint4*>(
          &ldsVT[buf][sg][c * 16 + m][32 + qd * 8]);
      bf16x8 bb1 = __builtin_bit_cast(bf16x8, b1);
      acc0[c] = MFMA16(fA1.f, bb1, acc0[c]);
      acc1[c] = MFMA16(fB1.f, bb1, acc1[c]);
    }

    if (step < 7) {
      uint4* dst =
          reinterpret_cast<uint4*>(&ldsVT[(step + 1) & 1][tg][vd][vh * 32]);
      dst[0] = n0;
      dst[1] = n1;
      dst[2] = n2;
      dst[3] = n3;
      __syncthreads();  // the ONLY barrier per step
    }
  }

  // --- per-wave denominator partials (broadcast across m lanes of C tile)
  if (m == 0) {
#pragma unroll
    for (int i = 0; i < 4; ++i) {
      drow[sg][rg][0][qd * 4 + i] = ad0[i];
      drow[sg][rg][1][qd * 4 + i] = ad1[i];
    }
  }
  // --- acc combine tree across the 4 S-groups (cmb overlays buf0 only)
  if (sg >= 2) {
    int z = rg * 2 + (sg - 2);
#pragma unroll
    for (int c = 0; c < 4; ++c)
#pragma unroll
      for (int i = 0; i < 4; ++i) {
        cmb[z][qd * 4 + i][c * 16 + m] = acc0[c][i];
        cmb[z][16 + qd * 4 + i][c * 16 + m] = acc1[c][i];
      }
  }
  __syncthreads();
  if (sg < 2) {
    int z = rg * 2 + sg;
#pragma unroll
    for (int c = 0; c < 4; ++c)
#pragma unroll
      for (int i = 0; i < 4; ++i) {
        acc0[c][i] += cmb[z][qd * 4 + i][c * 16 + m];
        acc1[c][i] += cmb[z][16 + qd * 4 + i][c * 16 + m];
      }
  }
  if (sg == 1) {  // write sg1+sg3 back to own zone (no cross-wave hazard)
    int z = rg * 2 + 1;
#pragma unroll
    for (int c = 0; c < 4; ++c)
#pragma unroll
      for (int i = 0; i < 4; ++i) {
        cmb[z][qd * 4 + i][c * 16 + m] = acc0[c][i];
        cmb[z][16 + qd * 4 + i][c * 16 + m] = acc1[c][i];
      }
  }
  __syncthreads();
  if (sg == 0) {
    int z = rg * 2 + 1;
    float inv0[4], inv1[4];
#pragma unroll
    for (int i = 0; i < 4; ++i) {
      int r = qd * 4 + i;
      inv0[i] = 1.0f / (drow[0][rg][0][r] + drow[1][rg][0][r] +
                        drow[2][rg][0][r] + drow[3][rg][0][r]);
      inv1[i] = 1.0f / (drow[0][rg][1][r] + drow[1][rg][1][r] +
                        drow[2][rg][1][r] + drow[3][rg][1][r]);
    }
    float* ob = out + ((size_t)(bh * L + l0 + rg * 32)) * DD;
#pragma unroll
    for (int c = 0; c < 4; ++c)
#pragma unroll
      for (int i = 0; i < 4; ++i) {
        float t0 = acc0[c][i] + cmb[z][qd * 4 + i][c * 16 + m];
        float t1 = acc1[c][i] + cmb[z][16 + qd * 4 + i][c * 16 + m];
        ob[(size_t)(qd * 4 + i) * DD + c * 16 + m] = t0 * inv0[i];
        ob[(size_t)(16 + qd * 4 + i) * DD + c * 16 + m] = t1 * inv1[i];
      }
  }
}

extern "C" void kernel_launch(void* const* d_in, const int* in_sizes, int n_in,
                              void* d_out, int out_size, void* d_ws,
                              size_t ws_size, hipStream_t stream) {
  const float* q = (const float*)d_in[0];
  const float* k = (const float*)d_in[1];
  const float* v = (const float*)d_in[2];
  float* out = (float*)d_out;
  float* ws = (float*)d_ws;

  float* ks = ws;  // BH*S = 32768 floats
  __hip_bfloat16* vt = (__hip_bfloat16*)(ws + BH * S);  // BH*DD*S bf16 = 4MB

  prep_kernel<<<2048 + 512, 256, 0, stream>>>(k, v, ks, vt);
  attn_kernel<<<dim3(L / BM, BH), 512, 0, stream>>>(q, vt, ks, out);
}

// Round 2
// 93.424 us; speedup vs baseline: 1.0420x; 1.0051x over previous
//
#include <hip/hip_runtime.h>
#include <hip/hip_bf16.h>

#define BH 16
#define L 2048
#define S 2048
#define DD 64
#define BM 64
#define BK 64
#define LDSPAD 8
#define LDW (BK + LDSPAD)   // prep kernel's LDS tile only

typedef __attribute__((ext_vector_type(4))) float f32x4;
typedef __bf16 bf16x8 __attribute__((ext_vector_type(8)));
typedef unsigned int u32;

union FragU {
  bf16x8 f;
  __hip_bfloat162 h2[4];
};

#define MFMA16(a, b, c) __builtin_amdgcn_mfma_f32_16x16x32_bf16((a), (b), (c), 0, 0, 0)

__device__ inline __hip_bfloat162 exp2pk(float al2, float nsl2, float k0,
                                         float k1) {
  float e0 = __builtin_amdgcn_exp2f(fmaf(al2, k0, nsl2));
  float e1 = __builtin_amdgcn_exp2f(fmaf(al2, k1, nsl2));
  return __float22bfloat162_rn(make_float2(e0, e1));
}

// async global->LDS, 16B per lane; LDS dest = wave-uniform base + lane*16
__device__ __forceinline__ void gload_lds16(const void* g, void* l) {
  __builtin_amdgcn_global_load_lds(
      (const __attribute__((address_space(1))) u32*)g,
      (__attribute__((address_space(3))) u32*)l, 16, 0, 0);
}

// ---------------------------------------------------------------------------
// prep: blocks [0,2048): K row sums (16 lanes per row).
//       blocks [2048,2560): V [bh][s][d] fp32 -> VT [bh][d][s] bf16 transpose.
// (unchanged; fully coalesced global side, modeled ~5-8us)
// ---------------------------------------------------------------------------
__global__ __launch_bounds__(256) void prep_kernel(
    const float* __restrict__ k, const float* __restrict__ v,
    float* __restrict__ ks, __hip_bfloat16* __restrict__ vt) {
  __shared__ __hip_bfloat16 tile[DD][LDW];
  int t = threadIdx.x;
  if (blockIdx.x < 2048) {
    int g = blockIdx.x * 256 + t;
    int row = g >> 4;
    int l16 = g & 15;
    float4 x = reinterpret_cast<const float4*>(k + (size_t)row * DD)[l16];
    float s = x.x + x.y + x.z + x.w;
    s += __shfl_xor(s, 1);
    s += __shfl_xor(s, 2);
    s += __shfl_xor(s, 4);
    s += __shfl_xor(s, 8);
    if (l16 == 0) ks[row] = s;
  } else {
    int bid = blockIdx.x - 2048;
    int s0 = (bid & 31) * 64;
    int bh = bid >> 5;
    int srow = t >> 4;
    int d4 = (t & 15) * 4;
#pragma unroll
    for (int kk = 0; kk < 4; ++kk) {
      int s = srow + kk * 16;
      float4 val = *reinterpret_cast<const float4*>(
          v + ((size_t)(bh * S + s0 + s)) * DD + d4);
      tile[d4 + 0][s] = __float2bfloat16(val.x);
      tile[d4 + 1][s] = __float2bfloat16(val.y);
      tile[d4 + 2][s] = __float2bfloat16(val.z);
      tile[d4 + 3][s] = __float2bfloat16(val.w);
    }
    __syncthreads();
    int dd = t >> 3;
    int j = t & 7;
#pragma unroll
    for (int kk = 0; kk < 2; ++kk) {
      int d = dd + kk * 32;
      uint4 val = *reinterpret_cast<const uint4*>(&tile[d][j * 8]);
      *reinterpret_cast<uint4*>(vt + ((size_t)(bh * DD + d)) * S + s0 + j * 8) =
          val;
    }
  }
}

// ---------------------------------------------------------------------------
// attn v3: 512 threads = 8 waves = 2 row-groups x 4 S-groups.
// VT staged by global_load_lds (no VGPR round-trip, no LDS-store instrs):
//   - LDS layout per tile: [64 rows][8 slots of 16B], row = 128B, LINEAR
//     (required by global_load_lds), tile = 8KB, group of 4 tiles = 32KB, x2 buf.
//   - bank-conflict fix via XOR swizzle, BOTH sides (rule 21):
//     data for (row, slot) is stored at slot' = slot ^ (row&7); the staging
//     global SOURCE address is permuted (col8 = (lane&7) ^ (lane>>3)) so the
//     linear LDS write lands it there; the ds_read applies the same XOR.
//     Verified: lane i, chunk c, wave w -> row=((w&1)*4+c)*8+(i>>3),
//     slot'=i&7 holds VT[row][ ((i&7)^(i>>3))*8 ..+8 ]; reader at (row, slot)
//     fetches slot^(row&7) -> original cols slot*8. Max 2-way bank alias.
// Denominators via MFMA vs all-ones B; combine tree overlays buf0 only
// (last step reads buf1, so no extra barrier needed before overlay writes).
// Target: VGPR <= 128 (launch_bounds 512,4 -> 2 blocks/CU) with NO spills.
// ---------------------------------------------------------------------------
__global__ __launch_bounds__(512, 4) void attn_kernel(
    const float* __restrict__ q, const __hip_bfloat16* __restrict__ vt,
    const float* __restrict__ ks, float* __restrict__ out) {
  int l0 = blockIdx.x * BM;
  int bh = blockIdx.y;

  __shared__ char smem[2 * 4 * 8192] __attribute__((aligned(16)));  // 64KB
  __shared__ float a_row[BM];
  __shared__ float red[16];
  __shared__ float drow[4][2][2][16];  // [sg][rg][rt][row]

  int t = threadIdx.x;
  int lane = t & 63;
  int w = t >> 6;   // 0..7
  int rg = w >> 2;  // row-group 0/1 (rows rg*32..rg*32+31)
  int sg = w & 3;   // S-group: this wave READS tile step*4+sg
  int m = lane & 15;
  int qd = lane >> 4;

  const __hip_bfloat16* vtb = vt + (size_t)bh * DD * S;
  const float* ksb = ks + (size_t)bh * S;
  const char* vtbc = (const char*)vtb;

  // per-lane invariant part of the staging source address:
  // row-within-chunk = lane>>3 (VT row stride = S*2 = 4096B),
  // 16B col chunk = (lane&7) ^ (lane>>3)  [inverse swizzle]
  const size_t laneg =
      (size_t)(lane >> 3) * (S * 2) + (size_t)(((lane & 7) ^ (lane >> 3)) << 4);
  // wave-uniform: this wave stages tile w>>1, rows (w&1)*32 .. +31
  const size_t wrowg = (size_t)((w & 1) * 32) * (S * 2);
  char* lwbase = smem + w * 4096;  // + buf*32768 + c*1024

  // stage group g (tiles g*4..g*4+3) into buffer b: 4 x 1KB per wave
#define STAGE(g, b)                                                         \
  {                                                                         \
    const char* gb0 =                                                       \
        vtbc + (size_t)(((g)*4 + (w >> 1)) * 64) * 2 + wrowg + laneg;       \
    char* lb0 = lwbase + (b)*32768;                                         \
    gload_lds16(gb0, lb0);                                                  \
    gload_lds16(gb0 + (size_t)8 * S * 2, lb0 + 1024);                       \
    gload_lds16(gb0 + (size_t)16 * S * 2, lb0 + 2048);                      \
    gload_lds16(gb0 + (size_t)24 * S * 2, lb0 + 3072);                      \
  }

  // --- prologue: stage group 0 (flies over the reductions below)
  STAGE(0, 0);

  int kb0 = sg * 64;
  float4 kA0 = *reinterpret_cast<const float4*>(ksb + kb0 + qd * 8);
  float4 kA1 = *reinterpret_cast<const float4*>(ksb + kb0 + qd * 8 + 4);
  float4 kB0 = *reinterpret_cast<const float4*>(ksb + kb0 + 32 + qd * 8);
  float4 kB1 = *reinterpret_cast<const float4*>(ksb + kb0 + 32 + qd * 8 + 4);

  // --- qsum for this block's 64 rows: 8 lanes per row
  {
    int r = t >> 3;
    int p = t & 7;
    const float* qp = q + ((size_t)(bh * L + l0 + r)) * DD + p * 8;
    float4 x0 = reinterpret_cast<const float4*>(qp)[0];
    float4 x1 = reinterpret_cast<const float4*>(qp)[1];
    float s = (x0.x + x0.y + x0.z + x0.w) + (x1.x + x1.y + x1.z + x1.w);
    s += __shfl_xor(s, 1);
    s += __shfl_xor(s, 2);
    s += __shfl_xor(s, 4);
    if (p == 0) a_row[r] = s;
  }

  // --- per-head kmax/kmin (per-block; sel cancels in the softmax ratio)
  {
    float4 y = *reinterpret_cast<const float4*>(ksb + t * 4);
    float mx = fmaxf(fmaxf(y.x, y.y), fmaxf(y.z, y.w));
    float mn = fminf(fminf(y.x, y.y), fminf(y.z, y.w));
#pragma unroll
    for (int off = 1; off < 64; off <<= 1) {
      mx = fmaxf(mx, __shfl_xor(mx, off));
      mn = fminf(mn, __shfl_xor(mn, off));
    }
    if (lane == 0) {
      red[w] = mx;
      red[8 + w] = mn;
    }
  }
  __syncthreads();  // drains vmcnt -> tile group 0 ready; publishes a_row/red

  float kmax = red[0], kmin = red[8];
#pragma unroll
  for (int i = 1; i < 8; ++i) {
    kmax = fmaxf(kmax, red[i]);
    kmin = fminf(kmin, red[8 + i]);
  }
  const float LOG2E = 1.44269504088896f;
  float ar0 = a_row[rg * 32 + m];
  float ar1 = a_row[rg * 32 + 16 + m];
  float al2_0 = ar0 * LOG2E, al2_1 = ar1 * LOG2E;
  float nsl2_0 = -al2_0 * ((ar0 > 0.f) ? kmax : kmin);
  float nsl2_1 = -al2_1 * ((ar1 > 0.f) ? kmax : kmin);

  FragU of;  // all-ones B fragment for denominator row-sum MFMAs
  {
    __hip_bfloat162 one2 = __float22bfloat162_rn(make_float2(1.f, 1.f));
    of.h2[0] = of.h2[1] = of.h2[2] = of.h2[3] = one2;
  }

  f32x4 acc0[4], acc1[4];
  f32x4 ad0 = (f32x4){0.f, 0.f, 0.f, 0.f};
  f32x4 ad1 = (f32x4){0.f, 0.f, 0.f, 0.f};
#pragma unroll
  for (int c = 0; c < 4; ++c) {
    acc0[c] = (f32x4){0.f, 0.f, 0.f, 0.f};
    acc1[c] = (f32x4){0.f, 0.f, 0.f, 0.f};
  }

  // swizzled read offset (constant per lane; row&7 == m&7 since rows are
  // c*16+m and 16 = 0 mod 8)
  const int sw0 = (qd ^ (m & 7)) << 4;

  for (int step = 0; step < 8; ++step) {
    int buf = step & 1;

    // async prefetch of next 4-tile group into the other buffer
    if (step < 7) STAGE(step + 1, buf ^ 1);

    // E fragments for this wave's tile (rows rg*32 + {0,16} + m)
    FragU fA0, fA1, fB0, fB1;
    fA0.h2[0] = exp2pk(al2_0, nsl2_0, kA0.x, kA0.y);
    fA0.h2[1] = exp2pk(al2_0, nsl2_0, kA0.z, kA0.w);
    fA0.h2[2] = exp2pk(al2_0, nsl2_0, kA1.x, kA1.y);
    fA0.h2[3] = exp2pk(al2_0, nsl2_0, kA1.z, kA1.w);
    fA1.h2[0] = exp2pk(al2_0, nsl2_0, kB0.x, kB0.y);
    fA1.h2[1] = exp2pk(al2_0, nsl2_0, kB0.z, kB0.w);
    fA1.h2[2] = exp2pk(al2_0, nsl2_0, kB1.x, kB1.y);
    fA1.h2[3] = exp2pk(al2_0, nsl2_0, kB1.z, kB1.w);
    fB0.h2[0] = exp2pk(al2_1, nsl2_1, kA0.x, kA0.y);
    fB0.h2[1] = exp2pk(al2_1, nsl2_1, kA0.z, kA0.w);
    fB0.h2[2] = exp2pk(al2_1, nsl2_1, kA1.x, kA1.y);
    fB0.h2[3] = exp2pk(al2_1, nsl2_1, kA1.z, kA1.w);
    fB1.h2[0] = exp2pk(al2_1, nsl2_1, kB0.x, kB0.y);
    fB1.h2[1] = exp2pk(al2_1, nsl2_1, kB0.z, kB0.w);
    fB1.h2[2] = exp2pk(al2_1, nsl2_1, kB1.x, kB1.y);
    fB1.h2[3] = exp2pk(al2_1, nsl2_1, kB1.z, kB1.w);

    // prefetch next ks chunk (old values consumed into fragments above)
    int kbn = ((step < 7) ? (step + 1) * 4 + sg : 28 + sg) * 64;
    kA0 = *reinterpret_cast<const float4*>(ksb + kbn + qd * 8);
    kA1 = *reinterpret_cast<const float4*>(ksb + kbn + qd * 8 + 4);
    kB0 = *reinterpret_cast<const float4*>(ksb + kbn + 32 + qd * 8);
    kB1 = *reinterpret_cast<const float4*>(ksb + kbn + 32 + qd * 8 + 4);

    // denominator row-sums on the MFMA pipe
    ad0 = MFMA16(fA0.f, of.f, ad0);
    ad0 = MFMA16(fA1.f, of.f, ad0);
    ad1 = MFMA16(fB0.f, of.f, ad1);
    ad1 = MFMA16(fB1.f, of.f, ad1);

    // PV MFMAs: swizzled ds_read_b128, shared by both row-tiles
    const char* rb = smem + buf * 32768 + sg * 8192;
#pragma unroll
    for (int c = 0; c < 4; ++c) {
      const char* rowp = rb + (c * 16 + m) * 128;
      uint4 b0 = *reinterpret_cast<const uint4*>(rowp + sw0);
      bf16x8 bb0 = __builtin_bit_cast(bf16x8, b0);
      acc0[c] = MFMA16(fA0.f, bb0, acc0[c]);
      acc1[c] = MFMA16(fB0.f, bb0, acc1[c]);
      uint4 b1 = *reinterpret_cast<const uint4*>(rowp + (sw0 ^ 64));
      bf16x8 bb1 = __builtin_bit_cast(bf16x8, b1);
      acc0[c] = MFMA16(fA1.f, bb1, acc0[c]);
      acc1[c] = MFMA16(fB1.f, bb1, acc1[c]);
    }

    if (step < 7) __syncthreads();  // drains staged loads; guards buf swap
  }

  // --- per-wave denominator partials
  if (m == 0) {
#pragma unroll
    for (int i = 0; i < 4; ++i) {
      drow[sg][rg][0][qd * 4 + i] = ad0[i];
      drow[sg][rg][1][qd * 4 + i] = ad1[i];
    }
  }

  // --- acc combine across the 4 S-groups; cmb overlays buf0 ONLY (last step
  // read buf1, so no barrier needed before these writes). Zone = 8KB.
  // col rotation (+4*r) keeps bank alias <= 2-way.
  auto cmb = [&](int z, int r, int col) -> float* {
    return reinterpret_cast<float*>(smem + z * 8192) + r * 64 +
           ((col + r * 4) & 63);
  };
  if (sg >= 2) {
    int z = rg * 2 + (sg - 2);
#pragma unroll
    for (int c = 0; c < 4; ++c)
#pragma unroll
      for (int i = 0; i < 4; ++i) {
        *cmb(z, qd * 4 + i, c * 16 + m) = acc0[c][i];
        *cmb(z, 16 + qd * 4 + i, c * 16 + m) = acc1[c][i];
      }
  }
  __syncthreads();
  if (sg < 2) {
    int z = rg * 2 + sg;
#pragma unroll
    for (int c = 0; c < 4; ++c)
#pragma unroll
      for (int i = 0; i < 4; ++i) {
        acc0[c][i] += *cmb(z, qd * 4 + i, c * 16 + m);
        acc1[c][i] += *cmb(z, 16 + qd * 4 + i, c * 16 + m);
      }
  }
  if (sg == 1) {  // write sg1+sg3 partial back to own zone
    int z = rg * 2 + 1;
#pragma unroll
    for (int c = 0; c < 4; ++c)
#pragma unroll
      for (int i = 0; i < 4; ++i) {
        *cmb(z, qd * 4 + i, c * 16 + m) = acc0[c][i];
        *cmb(z, 16 + qd * 4 + i, c * 16 + m) = acc1[c][i];
      }
  }
  __syncthreads();
  if (sg == 0) {
    int z = rg * 2 + 1;
    float inv0[4], inv1[4];
#pragma unroll
    for (int i = 0; i < 4; ++i) {
      int r = qd * 4 + i;
      inv0[i] = 1.0f / (drow[0][rg][0][r] + drow[1][rg][0][r] +
                        drow[2][rg][0][r] + drow[3][rg][0][r]);
      inv1[i] = 1.0f / (drow[0][rg][1][r] + drow[1][rg][1][r] +
                        drow[2][rg][1][r] + drow[3][rg][1][r]);
    }
    float* ob = out + ((size_t)(bh * L + l0 + rg * 32)) * DD;
#pragma unroll
    for (int c = 0; c < 4; ++c)
#pragma unroll
      for (int i = 0; i < 4; ++i) {
        float t0 = acc0[c][i] + *cmb(z, qd * 4 + i, c * 16 + m);
        float t1 = acc1[c][i] + *cmb(z, 16 + qd * 4 + i, c * 16 + m);
        ob[(size_t)(qd * 4 + i) * DD + c * 16 + m] = t0 * inv0[i];
        ob[(size_t)(16 + qd * 4 + i) * DD + c * 16 + m] = t1 * inv1[i];
      }
  }
#undef STAGE
}

extern "C" void kernel_launch(void* const* d_in, const int* in_sizes, int n_in,
                              void* d_out, int out_size, void* d_ws,
                              size_t ws_size, hipStream_t stream) {
  const float* q = (const float*)d_in[0];
  const float* k = (const float*)d_in[1];
  const float* v = (const float*)d_in[2];
  float* out = (float*)d_out;
  float* ws = (float*)d_ws;

  float* ks = ws;  // BH*S = 32768 floats
  __hip_bfloat16* vt = (__hip_bfloat16*)(ws + BH * S);  // BH*DD*S bf16 = 4MB

  prep_kernel<<<2048 + 512, 256, 0, stream>>>(k, v, ks, vt);
  attn_kernel<<<dim3(L / BM, BH), 512, 0, stream>>>(q, vt, ks, out);
}